// Round 18
// baseline (667.042 us; speedup 1.0000x reference)
//
#include <hip/hip_runtime.h>

#define B_    256
#define T_    200
#define C_    512
#define H_    8
#define HEAD_ 64
#define M_    (B_ * T_)          // 51200 rows
#define POS_OUT_ (M_ * C_)       // 26,214,400
#define QK_ROWS_ 208             // 200 padded to 13*16
#define VT_PAD_  224             // >= 7 k-steps * 32
#define P_PAD_   200             // LDS row stride (400 B ≡ 16 mod 128 -> 2-way banks = free; 16B-aligned)

typedef __attribute__((ext_vector_type(8))) _Float16 f16x8;
typedef __attribute__((ext_vector_type(4))) _Float16 f16x4;
typedef __attribute__((ext_vector_type(2))) _Float16 f16x2;
typedef __attribute__((ext_vector_type(4))) float f32x4;

// async global->LDS, 16B per lane; lds base must be wave-uniform
__device__ __forceinline__ void gload16(const void* g, void* l) {
    __builtin_amdgcn_global_load_lds(
        (const __attribute__((address_space(1))) unsigned int*)g,
        (__attribute__((address_space(3))) unsigned int*)l, 16, 0, 0);
}

// ---------------------------------------------------------------- gather + half-shift -> fp16 (float4, grid-stride)
__global__ __launch_bounds__(256) void gather_shift_k(
    const float* __restrict__ emb, const int* __restrict__ logs,
    _Float16* __restrict__ x)
{
    const int total = M_ * 128;           // 4 cols per thread-item
    for (int gid = blockIdx.x * 256 + threadIdx.x; gid < total; gid += gridDim.x * 256) {
        int bt = gid >> 7;
        int c  = (gid & 127) * 4;
        int t  = bt % T_;
        _Float16* xr = x + (size_t)bt * C_ + c;
        if (c < 256) {
            if (t == 0) {
                *(f16x4*)xr = (f16x4){(_Float16)0.f, (_Float16)0.f, (_Float16)0.f, (_Float16)0.f};
                continue;
            }
            float4 v = *(const float4*)(emb + (size_t)logs[bt - 1] * C_ + c);
            *(f16x4*)xr = (f16x4){(_Float16)v.x, (_Float16)v.y, (_Float16)v.z, (_Float16)v.w};
        } else {
            float4 v = *(const float4*)(emb + (size_t)logs[bt] * C_ + c);
            *(f16x4*)xr = (f16x4){(_Float16)v.x, (_Float16)v.y, (_Float16)v.z, (_Float16)v.w};
        }
    }
}

// ---------------------------------------------------------------- merged prologue: segmented grid, all segments independent
// [0,1024): Wq/Wk/Wv/Wo fp32->fp16            -> Wh[4][512][512]
// [1024,2376): wtabT[g][s][t]=tw*ta*tb         (1352 blocks; TRANSPOSED:
//              s-major so attn's 4 t-values are one float4)
// [2376,2576): zero neg-logit region of out    (200 blocks)
// [2576,2576+cb8): zero pads of Qb/Kb/Vt       (cb8 blocks)
// [.., +13): RoPE table rtab[t][c] = {cos,sin}(t*10000^(-c/16))
__global__ __launch_bounds__(256) void prologue_k(
    const float* __restrict__ Wq, const float* __restrict__ Wk,
    const float* __restrict__ Wv, const float* __restrict__ Wo,
    _Float16* __restrict__ Wh,
    const float* __restrict__ tw, const float* __restrict__ ta,
    const float* __restrict__ tb, float* __restrict__ wtab,
    float* __restrict__ out,
    _Float16* __restrict__ Qb, _Float16* __restrict__ Kb, _Float16* __restrict__ Vt,
    float2* __restrict__ rtab, int cb8)
{
    int bid = blockIdx.x, tid = threadIdx.x;
    if (bid < 1024) {
        int idx = bid * 256 + tid;
        int mat = idx >> 16;
        int off = (idx & 65535) << 2;
        const float* src = (mat == 0) ? Wq : (mat == 1) ? Wk : (mat == 2) ? Wv : Wo;
        float4 v = *(const float4*)(src + off);
        f16x4 o = { (_Float16)v.x, (_Float16)v.y, (_Float16)v.z, (_Float16)v.w };
        *(f16x4*)(Wh + ((size_t)mat << 18) + off) = o;
    } else if (bid < 1024 + 1352) {
        int idx = (bid - 1024) * 256 + tid;     // 8*208*208 = 346112
        if (idx < 8 * 208 * 208) {
            int g   = idx / (208 * 208);
            int rem = idx % (208 * 208);
            int s = rem / 208, t = rem % 208;   // TRANSPOSED: s-major
            int tt = min(t, 199), ss = min(s, 199);
            int wi = min(max(199 - tt + ss, 0), 199);
            wtab[idx] = tw[g * 200 + wi] * ta[g * 200 + ss] * tb[g * 200 + tt];
        }
    } else if (bid < 1024 + 1352 + 200) {
        int idx = (bid - 1024 - 1352) * 256 + tid;
        out[(size_t)POS_OUT_ + idx] = 0.0f;
    } else if (bid < 1024 + 1352 + 200 + cb8) {
        int bh = bid - 1024 - 1352 - 200;
        for (int idx = tid; idx < 8 * 64; idx += 256) {        // rows 200..207
            Qb[(size_t)bh * QK_ROWS_ * 64 + 200 * 64 + idx] = (_Float16)0.0f;
            Kb[(size_t)bh * QK_ROWS_ * 64 + 200 * 64 + idx] = (_Float16)0.0f;
        }
        for (int idx = tid; idx < 64 * (VT_PAD_ - 200); idx += 256) {  // cols 200..223
            int d = idx / (VT_PAD_ - 200), s = 200 + idx % (VT_PAD_ - 200);
            Vt[(size_t)bh * 64 * VT_PAD_ + (size_t)d * VT_PAD_ + s] = (_Float16)0.0f;
        }
    } else {
        int idx = (bid - 1024 - 1352 - 200 - cb8) * 256 + tid;  // 200*16 = 3200
        if (idx < 3200) {
            int t = idx >> 4, c = idx & 15;
            float ang = (float)t * powf(10000.0f, -(float)c / 16.0f);
            rtab[idx] = (float2){cosf(ang), sinf(ang)};
        }
    }
}

// ---------------------------------------------------------------- fused QKV GEMM (MFMA fp16, depth-2 counted-vmcnt pipeline, T2 swizzle)
// launch_bounds(256,3): allocator trims to ~68 VGPR + 64 acc -> 3 waves/SIMD
// (r14: occ 20->30%). RoPE cos/sin from precomputed rtab (no sincosf).
__global__ __launch_bounds__(256, 3) void gemm_qkv_k(
    const _Float16* __restrict__ xh,
    const _Float16* __restrict__ Wh,    // [3][512][512]
    const float* __restrict__ bq, const float* __restrict__ bk, const float* __restrict__ bv,
    const float2* __restrict__ rtab,    // [200][16] {cos,sin}
    _Float16* __restrict__ Qb, _Float16* __restrict__ Kb,
    _Float16* __restrict__ Vt,
    int nmt)
{
    int n = blockIdx.x;
    int mt, v;
    if ((nmt & 7) == 0) { int q8 = n & 7, i = n >> 3; mt = (i / 12) * 8 + q8; v = i % 12; }
    else               { mt = n / 12; v = n % 12; }
    int which = v >> 2;            // 0=Q 1=K 2=V
    int nt    = v & 3;             // n-tile (128 cols = 2 heads)
    int m0    = mt * 128;
    const _Float16* Wm = Wh + ((size_t)(which * 4 + nt) * 128) * 512;
    const float* bias = (which == 0) ? bq : (which == 1) ? bk : bv;

    __shared__ _Float16 As[3][128 * 32];
    __shared__ _Float16 Bs[3][128 * 32];

    int tid  = threadIdx.x;
    int w    = tid >> 6, lane = tid & 63;
    int quad = lane >> 4, l15 = lane & 15;
    int wm   = w >> 1,    wn  = w & 1;
    int srow = lane >> 2, scg = lane & 3;        // staging: row-in-seg, 16B colgroup (LDS slot)
    int scg_src = scg ^ ((srow >> 1) & 3);       // pre-swizzled global colgroup
    int rq = (l15 >> 1) & 3;                     // read-side swizzle term

    auto stage = [&](int buf, int k0) {
#pragma unroll
        for (int rr = 0; rr < 2; ++rr) {
            int seg = rr * 4 + w;               // 8 segments of 16 rows
            int row = seg * 16 + srow;
            gload16(xh + (size_t)(m0 + row) * 512 + k0 + scg_src * 8, As[buf] + seg * 512);
            gload16(Wm + (size_t)row * 512 + k0 + scg_src * 8, Bs[buf] + seg * 512);
        }
    };

    f32x4 acc[4][4];
#pragma unroll
    for (int m = 0; m < 4; ++m)
#pragma unroll
        for (int nn = 0; nn < 4; ++nn) acc[m][nn] = (f32x4){0.f, 0.f, 0.f, 0.f};

    stage(0, 0);
    stage(1, 32);
#pragma unroll
    for (int s = 0; s < 16; ++s) {
        if (s < 15) asm volatile("s_waitcnt vmcnt(4)" ::: "memory");
        else        asm volatile("s_waitcnt vmcnt(0)" ::: "memory");
        __builtin_amdgcn_s_barrier();
        __builtin_amdgcn_sched_barrier(0);
        const _Float16* Ab = As[s % 3];
        const _Float16* Bb = Bs[s % 3];
        f16x8 af[4], bf[4];
#pragma unroll
        for (int m = 0; m < 4; ++m)
            af[m] = *(const f16x8*)(Ab + (wm * 4 + m) * 512 + l15 * 32 + (quad ^ rq) * 8);
#pragma unroll
        for (int nn = 0; nn < 4; ++nn)
            bf[nn] = *(const f16x8*)(Bb + (wn * 4 + nn) * 512 + l15 * 32 + (quad ^ rq) * 8);
        if (s <= 13) stage((s + 2) % 3, (s + 2) * 32);
#pragma unroll
        for (int m = 0; m < 4; ++m)
#pragma unroll
            for (int nn = 0; nn < 4; ++nn)
                acc[m][nn] = __builtin_amdgcn_mfma_f32_16x16x32_f16(af[m], bf[nn], acc[m][nn], 0, 0, 0);
    }

    int h = nt * 2 + wn;   // head within matrix
    if (which < 2) {
        _Float16* dst = (which == 0) ? Qb : Kb;
        float sc = (which == 0) ? 0.125f : 1.0f;
#pragma unroll
        for (int m = 0; m < 4; ++m) {
#pragma unroll
            for (int r = 0; r < 4; ++r) {
                int row = m0 + wm * 64 + m * 16 + quad * 4 + r;
                int bl = row / T_, t = row % T_;
                float2 cssn = rtab[t * 16 + l15];
                float cs = cssn.x, sn = cssn.y;
                size_t base = ((size_t)(bl * 8 + h) * QK_ROWS_ + t) * 64;
                float av = acc[m][0][r] + bias[h * 64 + l15];
                float bv2 = acc[m][1][r] + bias[h * 64 + 16 + l15];
                dst[base + l15]      = (_Float16)((av * cs - bv2 * sn) * sc);
                dst[base + 16 + l15] = (_Float16)((bv2 * cs + av * sn) * sc);
                dst[base + 32 + l15] = (_Float16)((acc[m][2][r] + bias[h * 64 + 32 + l15]) * sc);
                dst[base + 48 + l15] = (_Float16)((acc[m][3][r] + bias[h * 64 + 48 + l15]) * sc);
            }
        }
    } else {
        // V: transpose-store to Vt[b][h][d][s]
#pragma unroll
        for (int nn = 0; nn < 4; ++nn) {
            int ch = nn * 16 + l15;
            float bval = bias[h * 64 + ch];
#pragma unroll
            for (int m = 0; m < 4; ++m) {
                int r0 = m0 + wm * 64 + m * 16 + quad * 4;   // 4 consecutive rows, %4==0
                int t0v = r0 % T_;
                if (t0v <= 196) {
                    int bl = r0 / T_;
                    f16x4 v4 = {(_Float16)(acc[m][nn][0] + bval),
                                (_Float16)(acc[m][nn][1] + bval),
                                (_Float16)(acc[m][nn][2] + bval),
                                (_Float16)(acc[m][nn][3] + bval)};
                    *(f16x4*)(Vt + ((size_t)(bl * 8 + h) * 64 + ch) * VT_PAD_ + t0v) = v4;
                } else {
#pragma unroll
                    for (int r = 0; r < 4; ++r) {
                        int rw = r0 + r;
                        int bl = rw / T_, s = rw % T_;
                        Vt[((size_t)(bl * 8 + h) * 64 + ch) * VT_PAD_ + s] = (_Float16)(acc[m][nn][r] + bval);
                    }
                }
            }
        }
    }
}

// ---------------------------------------------------------------- fused MFMA attention (512 thr, 8 waves, 1 head/wave; fp16)
// flat grid 13*CB, XCD-swizzled (b locality) + LPT heavy-first.
// launch_bounds(512,4): (512,6) spills (r15: VGPR 60->40, WRITE 51->169MB).
// wtab TRANSPOSED [g][s][t]: per s-tile the 4 t-values are one float4 load
// (was 4 scalar dwords at stride 832B) -> 52 -> 13 VMEM ops in phase 1.
__global__ __launch_bounds__(512, 4) void attn_fused_k(
    const _Float16* __restrict__ Qb, const _Float16* __restrict__ Kb,
    const _Float16* __restrict__ Vt,
    const float* __restrict__ wtab,   // [8][208 s][208 t]
    const float* __restrict__ wmix,
    _Float16* __restrict__ ao)
{
    int n    = blockIdx.x;
    int xcd  = n & 7, slot = n >> 3;
    int i_tile = 12 - (slot % 13);       // LPT: heaviest (nst=13) dispatched first
    int b      = (slot / 13) * 8 + xcd;

    int tid  = threadIdx.x;
    int wave = tid >> 6, lane = tid & 63;
    int quad = lane >> 4, l15 = lane & 15;
    int t0   = i_tile * 16;
    int nst  = i_tile + 1;         // s-tiles needed (s <= t0+15)
    int smax = nst * 16;
    int lim  = smax < 200 ? smax : 200;  // valid P columns

    __shared__ _Float16 Pt[8][16][P_PAD_];         // 51,200 B
    __shared__ float mixs[64];                     //    256 B
    __shared__ f16x2 invt[8][16];                  //    512 B

    if (tid < 64) mixs[tid] = wmix[tid];

    // ---- phase 1: QK^T -> exp -> *w -> Pt (unnormalized); wave = head g
    {
        int g = wave;
        int trow = quad * 4;
        const _Float16* Qg = Qb + (size_t)(b * 8 + g) * QK_ROWS_ * 64;
        const _Float16* Kg = Kb + (size_t)(b * 8 + g) * QK_ROWS_ * 64;
        f16x8 a0 = *(const f16x8*)(Qg + (size_t)(t0 + l15) * 64 + quad * 8);
        f16x8 a1 = *(const f16x8*)(Qg + (size_t)(t0 + l15) * 64 + quad * 8 + 32);
        // transposed: wg + s*208 is the float4 of t-values for this thread
        const float* wg = wtab + (size_t)g * 208 * 208 + t0 + trow;

        // rolling depth-2 ring (compile-time st%3 indices)
        f16x8 kr0[3], kr1[3];
        f32x4 wr[3];
        kr0[0] = *(const f16x8*)(Kg + (size_t)l15 * 64 + quad * 8);
        kr1[0] = *(const f16x8*)(Kg + (size_t)l15 * 64 + quad * 8 + 32);
        wr[0]  = *(const f32x4*)(wg + (size_t)l15 * 208);
        if (nst > 1) {
            kr0[1] = *(const f16x8*)(Kg + (size_t)(16 + l15) * 64 + quad * 8);
            kr1[1] = *(const f16x8*)(Kg + (size_t)(16 + l15) * 64 + quad * 8 + 32);
            wr[1]  = *(const f32x4*)(wg + (size_t)(16 + l15) * 208);
        }
        __builtin_amdgcn_sched_barrier(0);   // pin prologue load issue

        float sum[4] = {0.f, 0.f, 0.f, 0.f};
        __builtin_amdgcn_s_setprio(1);
#pragma unroll
        for (int st = 0; st < 13; ++st) if (st < nst) {
            if (st + 2 < nst) {              // prefetch st+2 before consuming st
                int sl = (st + 2) % 3;
                kr0[sl] = *(const f16x8*)(Kg + (size_t)((st + 2) * 16 + l15) * 64 + quad * 8);
                kr1[sl] = *(const f16x8*)(Kg + (size_t)((st + 2) * 16 + l15) * 64 + quad * 8 + 32);
                wr[sl]  = *(const f32x4*)(wg + (size_t)((st + 2) * 16 + l15) * 208);
                __builtin_amdgcn_sched_barrier(0);   // don't sink the prefetch
            }
            int cl = st % 3;
            f32x4 c = {0.f, 0.f, 0.f, 0.f};
            c = __builtin_amdgcn_mfma_f32_16x16x32_f16(a0, kr0[cl], c, 0, 0, 0);
            c = __builtin_amdgcn_mfma_f32_16x16x32_f16(a1, kr1[cl], c, 0, 0, 0);
            int s = st * 16 + l15;
            bool diag = (st == nst - 1);
#pragma unroll
            for (int r = 0; r < 4; ++r) {
                int t = t0 + trow + r;
                float e = (!diag || s <= t) ? __expf(c[r]) : 0.f;
                sum[r] += e;
                if (s < 200) Pt[g][trow + r][s] = (_Float16)(e * wr[cl][r]);
            }
        }
        __builtin_amdgcn_s_setprio(0);
#pragma unroll
        for (int r = 0; r < 4; ++r) {
            float sm = sum[r];
            sm += __shfl_xor(sm, 1);
            sm += __shfl_xor(sm, 2);
            sm += __shfl_xor(sm, 4);
            sm += __shfl_xor(sm, 8);
            if (l15 == 0) {
                _Float16 ih = (_Float16)(1.0f / sm);
                invt[g][trow + r] = (f16x2){ih, ih};
            }
        }
    }
    __syncthreads();

    // ---- phase 2: normalize (×invt) + in-place 8x8 head mix, packed f16x2
    {
        f16x2 mx[64];
#pragma unroll
        for (int i = 0; i < 64; ++i) {
            _Float16 mh = (_Float16)mixs[i];
            mx[i] = (f16x2){mh, mh};
        }
        int nitems = lim << 3;             // 16 tloc x (lim/2) pairs
        for (int idx = tid; idx < nitems; idx += 512) {
            int tloc = idx & 15;
            int sp   = (idx >> 4) << 1;    // even s, < lim <= 200
            f16x2 pv[8];
#pragma unroll
            for (int g = 0; g < 8; ++g) pv[g] = *(const f16x2*)&Pt[g][tloc][sp];
#pragma unroll
            for (int g = 0; g < 8; ++g) pv[g] = pv[g] * invt[g][tloc];
#pragma unroll
            for (int ho = 0; ho < 8; ++ho) {
                f16x2 o = mx[ho * 8] * pv[0];
#pragma unroll
                for (int g = 1; g < 8; ++g) o += mx[ho * 8 + g] * pv[g];
                *(f16x2*)&Pt[ho][tloc][sp] = o;
            }
        }
    }
    __syncthreads();

    // ---- phase 3: PV via MFMA (fp16); wave = head. A-frag slots cc >= lim
    // are masked/nonexistent -> zero (b*0=0; Vt zero-padded past 200).
    // V prefetched depth-2 with pinned issue.
    {
        int nk = (nst + 1) >> 1;       // k-steps of 32 over s
        int hda = wave;
        const _Float16* Vh = Vt + (size_t)(b * 8 + hda) * 64 * VT_PAD_;
        f32x4 c4[4];
#pragma unroll
        for (int n2 = 0; n2 < 4; ++n2) c4[n2] = (f32x4){0.f, 0.f, 0.f, 0.f};
        f16x8 vb[2][4];
#pragma unroll
        for (int n2 = 0; n2 < 4; ++n2)
            vb[0][n2] = *(const f16x8*)(Vh + (size_t)(n2 * 16 + l15) * VT_PAD_ + quad * 8);
        __builtin_amdgcn_s_setprio(1);
#pragma unroll
        for (int ks = 0; ks < 7; ++ks) if (ks < nk) {
            if (ks + 1 < nk) {
#pragma unroll
                for (int n2 = 0; n2 < 4; ++n2)
                    vb[(ks + 1) & 1][n2] = *(const f16x8*)(Vh + (size_t)(n2 * 16 + l15) * VT_PAD_ + (ks + 1) * 32 + quad * 8);
                __builtin_amdgcn_sched_barrier(0);   // don't sink the prefetch
            }
            int cc = ks * 32 + quad * 8;
            bool oob = cc >= lim;
            int cl = oob ? 0 : cc;
            f16x8 a = *(const f16x8*)(&Pt[hda][l15][cl]);
            if (oob) {
#pragma unroll
                for (int j = 0; j < 8; ++j) a[j] = (_Float16)0.0f;
            }
#pragma unroll
            for (int n2 = 0; n2 < 4; ++n2)
                c4[n2] = __builtin_amdgcn_mfma_f32_16x16x32_f16(a, vb[ks & 1][n2], c4[n2], 0, 0, 0);
        }
        __builtin_amdgcn_s_setprio(0);
#pragma unroll
        for (int n2 = 0; n2 < 4; ++n2)
#pragma unroll
            for (int r = 0; r < 4; ++r) {
                int t = t0 + quad * 4 + r;
                if (t < 200)
                    ao[((size_t)(b * T_ + t)) * 512 + hda * 64 + n2 * 16 + l15] = (_Float16)c4[n2][r];
            }
    }
}

// ---------------------------------------------------------------- out projection (MFMA fp16, pipeline, T2 swizzle) * gamma,
// FUSED with pos/neg logits: po = val*pe written directly; neg partials
// (64-col slices) reduced over l15 and atomicAdd'ed. No lf buffer.
__global__ __launch_bounds__(256, 3) void gemm_out_k(
    const _Float16* __restrict__ Ah, const _Float16* __restrict__ Woh,
    const float* __restrict__ bo, const float* __restrict__ gamma,
    const float* __restrict__ emb, const int* __restrict__ pos,
    const int* __restrict__ neg, float* __restrict__ out,
    int bt0, int nmt)
{
    int n = blockIdx.x;
    int mt, nt;
    if ((nmt & 7) == 0) { int q8 = n & 7, i = n >> 3; mt = (i / 4) * 8 + q8; nt = i % 4; }
    else               { mt = n / 4; nt = n % 4; }
    int m0 = mt * 128;
    const _Float16* Wm = Woh + (size_t)nt * 128 * 512;

    __shared__ _Float16 As[3][128 * 32];
    __shared__ _Float16 Bs[3][128 * 32];

    int tid  = threadIdx.x;
    int w    = tid >> 6, lane = tid & 63;
    int quad = lane >> 4, l15 = lane & 15;
    int wm   = w >> 1,    wn  = w & 1;
    int srow = lane >> 2, scg = lane & 3;
    int scg_src = scg ^ ((srow >> 1) & 3);
    int rq = (l15 >> 1) & 3;

    auto stage = [&](int buf, int k0) {
#pragma unroll
        for (int rr = 0; rr < 2; ++rr) {
            int seg = rr * 4 + w;
            int row = seg * 16 + srow;
            gload16(Ah + (size_t)(m0 + row) * 512 + k0 + scg_src * 8, As[buf] + seg * 512);
            gload16(Wm + (size_t)row * 512 + k0 + scg_src * 8, Bs[buf] + seg * 512);
        }
    };

    f32x4 acc[4][4];
#pragma unroll
    for (int m = 0; m < 4; ++m)
#pragma unroll
        for (int nn = 0; nn < 4; ++nn) acc[m][nn] = (f32x4){0.f, 0.f, 0.f, 0.f};

    stage(0, 0);
    stage(1, 32);
#pragma unroll
    for (int s = 0; s < 16; ++s) {
        if (s < 15) asm volatile("s_waitcnt vmcnt(4)" ::: "memory");
        else        asm volatile("s_waitcnt vmcnt(0)" ::: "memory");
        __builtin_amdgcn_s_barrier();
        __builtin_amdgcn_sched_barrier(0);
        const _Float16* Ab = As[s % 3];
        const _Float16* Bb = Bs[s % 3];
        f16x8 af[4], bf[4];
#pragma unroll
        for (int m = 0; m < 4; ++m)
            af[m] = *(const f16x8*)(Ab + (wm * 4 + m) * 512 + l15 * 32 + (quad ^ rq) * 8);
#pragma unroll
        for (int nn = 0; nn < 4; ++nn)
            bf[nn] = *(const f16x8*)(Bb + (wn * 4 + nn) * 512 + l15 * 32 + (quad ^ rq) * 8);
        if (s <= 13) stage((s + 2) % 3, (s + 2) * 32);
#pragma unroll
        for (int m = 0; m < 4; ++m)
#pragma unroll
            for (int nn = 0; nn < 4; ++nn)
                acc[m][nn] = __builtin_amdgcn_mfma_f32_16x16x32_f16(af[m], bf[nn], acc[m][nn], 0, 0, 0);
    }

    // fused epilogue: lf = (acc+bo)*gamma; po = lf*pe; neg += lf.ne (atomic)
#pragma unroll
    for (int m = 0; m < 4; ++m) {
#pragma unroll
        for (int r = 0; r < 4; ++r) {
            int row = m0 + wm * 64 + m * 16 + quad * 4 + r;
            float gg = gamma[row % T_];
            int pr = pos[row], nr = neg[row];
            const float* pe = emb + (size_t)pr * 512;
            const float* ne = emb + (size_t)nr * 512;
            float* po = out + (size_t)(bt0 + row) * 512;
            float s = 0.f;
#pragma unroll
            for (int nn = 0; nn < 4; ++nn) {
                int col = nt * 128 + wn * 64 + nn * 16 + l15;
                float val = (acc[m][nn][r] + bo[col]) * gg;
                po[col] = val * pe[col];
                s += val * ne[col];
            }
            s += __shfl_xor(s, 1);
            s += __shfl_xor(s, 2);
            s += __shfl_xor(s, 4);
            s += __shfl_xor(s, 8);
            if (l15 == 0)
                atomicAdd(out + (size_t)POS_OUT_ + bt0 + row, s);
        }
    }
}

// ----------------------------------------------------------------
extern "C" void kernel_launch(void* const* d_in, const int* in_sizes, int n_in,
                              void* d_out, int out_size, void* d_ws, size_t ws_size,
                              hipStream_t stream)
{
    const int* logs = (const int*)d_in[1];
    const int* pos  = (const int*)d_in[2];
    const int* neg  = (const int*)d_in[3];
    const float* emb = (const float*)d_in[4];
    const float* tw  = (const float*)d_in[5];
    const float* ta  = (const float*)d_in[6];
    const float* tb  = (const float*)d_in[7];
    const float* tg  = (const float*)d_in[8];
    const float* Wq  = (const float*)d_in[9];
    const float* bq  = (const float*)d_in[10];
    const float* Wk  = (const float*)d_in[11];
    const float* bk  = (const float*)d_in[12];
    const float* Wv  = (const float*)d_in[13];
    const float* bv  = (const float*)d_in[14];
    const float* wmix= (const float*)d_in[15];
    const float* Wo  = (const float*)d_in[16];
    const float* bo  = (const float*)d_in[17];

    // Per-b buffer bytes: xh + Qb + Kb + Vt + ao(fp16)
    const size_t PER_B = (size_t)T_ * C_ * 2            // xh      204,800
                       + (size_t)8 * QK_ROWS_ * 64 * 2  // Qb      212,992
                       + (size_t)8 * QK_ROWS_ * 64 * 2  // Kb      212,992
                       + (size_t)8 * 64 * VT_PAD_ * 2   // Vt      229,376
                       + (size_t)T_ * C_ * 2;           // ao      204,800
    const size_t SZ_WH = (size_t)4 * 512 * 512 * 2;     // 2,097,152
    const size_t SZ_WT = (size_t)8 * 208 * 208 * 4;     // 1,384,448
    const size_t SZ_RT = (size_t)200 * 16 * 8;          //    25,600

    int CB = (ws_size >= SZ_WH + SZ_WT + SZ_RT + PER_B * B_) ? B_ : 32;
    int nch = B_ / CB;
    int CM = CB * T_;
    int NMT = CM / 128;            // m-tiles

    char* p = (char*)d_ws;
    _Float16*       Wh   = (_Float16*)p;  p += SZ_WH;
    float*          wtab = (float*)p;     p += SZ_WT;
    float2*         rtab = (float2*)p;    p += SZ_RT;
    _Float16*       xh   = (_Float16*)p;  p += (size_t)CM * C_ * 2;
    _Float16*       Qb   = (_Float16*)p;  p += (size_t)CB * 8 * QK_ROWS_ * 64 * 2;
    _Float16*       Kb   = (_Float16*)p;  p += (size_t)CB * 8 * QK_ROWS_ * 64 * 2;
    _Float16*       Vt   = (_Float16*)p;  p += (size_t)CB * 8 * 64 * VT_PAD_ * 2;
    _Float16*       aoh  = (_Float16*)p;

    int cb8 = CB * 8;
    int npro = 1024 + 1352 + 200 + cb8 + 13;
    prologue_k<<<npro, 256, 0, stream>>>(Wq, Wk, Wv, Wo, Wh, tw, ta, tb, wtab,
                                         (float*)d_out, Qb, Kb, Vt, rtab, cb8);

    for (int c = 0; c < nch; ++c) {
        int bt0 = c * CM;
        gather_shift_k<<<2048, 256, 0, stream>>>(emb, logs + bt0, xh);
        gemm_qkv_k<<<NMT * 12, 256, 0, stream>>>(xh, Wh, bq, bk, bv, rtab, Qb, Kb, Vt, NMT);
        attn_fused_k<<<13 * CB, 512, 0, stream>>>(Qb, Kb, Vt, wtab, wmix, aoh);
        gemm_out_k<<<NMT * 4, 256, 0, stream>>>(aoh, Wh + (size_t)3 * 512 * 512, bo, tg,
                                                emb, pos + bt0, neg + bt0, (float*)d_out, bt0, NMT);
    }
}

// Round 19
// 649.374 us; speedup vs baseline: 1.0272x; 1.0272x over previous
//
#include <hip/hip_runtime.h>

#define B_    256
#define T_    200
#define C_    512
#define H_    8
#define HEAD_ 64
#define M_    (B_ * T_)          // 51200 rows
#define POS_OUT_ (M_ * C_)       // 26,214,400
#define QK_ROWS_ 208             // 200 padded to 13*16
#define VT_PAD_  224             // >= 7 k-steps * 32
#define P_PAD_   200             // LDS row stride (400 B ≡ 16 mod 128 -> 2-way banks = free; 16B-aligned)

typedef __attribute__((ext_vector_type(8))) _Float16 f16x8;
typedef __attribute__((ext_vector_type(4))) _Float16 f16x4;
typedef __attribute__((ext_vector_type(2))) _Float16 f16x2;
typedef __attribute__((ext_vector_type(4))) float f32x4;

// async global->LDS, 16B per lane; lds base must be wave-uniform
__device__ __forceinline__ void gload16(const void* g, void* l) {
    __builtin_amdgcn_global_load_lds(
        (const __attribute__((address_space(1))) unsigned int*)g,
        (__attribute__((address_space(3))) unsigned int*)l, 16, 0, 0);
}

// ---------------------------------------------------------------- gather + half-shift -> fp16 (float4, grid-stride)
__global__ __launch_bounds__(256) void gather_shift_k(
    const float* __restrict__ emb, const int* __restrict__ logs,
    _Float16* __restrict__ x)
{
    const int total = M_ * 128;           // 4 cols per thread-item
    for (int gid = blockIdx.x * 256 + threadIdx.x; gid < total; gid += gridDim.x * 256) {
        int bt = gid >> 7;
        int c  = (gid & 127) * 4;
        int t  = bt % T_;
        _Float16* xr = x + (size_t)bt * C_ + c;
        if (c < 256) {
            if (t == 0) {
                *(f16x4*)xr = (f16x4){(_Float16)0.f, (_Float16)0.f, (_Float16)0.f, (_Float16)0.f};
                continue;
            }
            float4 v = *(const float4*)(emb + (size_t)logs[bt - 1] * C_ + c);
            *(f16x4*)xr = (f16x4){(_Float16)v.x, (_Float16)v.y, (_Float16)v.z, (_Float16)v.w};
        } else {
            float4 v = *(const float4*)(emb + (size_t)logs[bt] * C_ + c);
            *(f16x4*)xr = (f16x4){(_Float16)v.x, (_Float16)v.y, (_Float16)v.z, (_Float16)v.w};
        }
    }
}

// ---------------------------------------------------------------- merged prologue: segmented grid, all segments independent
// [0,1024): Wq/Wk/Wv/Wo fp32->fp16            -> Wh[4][512][512]
// [1024,2376): wtab[g][t][s]=tw*ta*tb          (1352 blocks)
// [2376,2576): zero neg-logit region of out    (200 blocks)
// [2576,2576+cb8): zero pads of Qb/Kb/Vt       (cb8 blocks)
// [.., +13): RoPE table rtab[t][c] = {cos,sin}(t*10000^(-c/16))
__global__ __launch_bounds__(256) void prologue_k(
    const float* __restrict__ Wq, const float* __restrict__ Wk,
    const float* __restrict__ Wv, const float* __restrict__ Wo,
    _Float16* __restrict__ Wh,
    const float* __restrict__ tw, const float* __restrict__ ta,
    const float* __restrict__ tb, float* __restrict__ wtab,
    float* __restrict__ out,
    _Float16* __restrict__ Qb, _Float16* __restrict__ Kb, _Float16* __restrict__ Vt,
    float2* __restrict__ rtab, int cb8)
{
    int bid = blockIdx.x, tid = threadIdx.x;
    if (bid < 1024) {
        int idx = bid * 256 + tid;
        int mat = idx >> 16;
        int off = (idx & 65535) << 2;
        const float* src = (mat == 0) ? Wq : (mat == 1) ? Wk : (mat == 2) ? Wv : Wo;
        float4 v = *(const float4*)(src + off);
        f16x4 o = { (_Float16)v.x, (_Float16)v.y, (_Float16)v.z, (_Float16)v.w };
        *(f16x4*)(Wh + ((size_t)mat << 18) + off) = o;
    } else if (bid < 1024 + 1352) {
        int idx = (bid - 1024) * 256 + tid;     // 8*208*208 = 346112
        if (idx < 8 * 208 * 208) {
            int g   = idx / (208 * 208);
            int rem = idx % (208 * 208);
            int t = rem / 208, s = rem % 208;
            int tt = min(t, 199), ss = min(s, 199);
            int wi = min(max(199 - tt + ss, 0), 199);
            wtab[idx] = tw[g * 200 + wi] * ta[g * 200 + ss] * tb[g * 200 + tt];
        }
    } else if (bid < 1024 + 1352 + 200) {
        int idx = (bid - 1024 - 1352) * 256 + tid;
        out[(size_t)POS_OUT_ + idx] = 0.0f;
    } else if (bid < 1024 + 1352 + 200 + cb8) {
        int bh = bid - 1024 - 1352 - 200;
        for (int idx = tid; idx < 8 * 64; idx += 256) {        // rows 200..207
            Qb[(size_t)bh * QK_ROWS_ * 64 + 200 * 64 + idx] = (_Float16)0.0f;
            Kb[(size_t)bh * QK_ROWS_ * 64 + 200 * 64 + idx] = (_Float16)0.0f;
        }
        for (int idx = tid; idx < 64 * (VT_PAD_ - 200); idx += 256) {  // cols 200..223
            int d = idx / (VT_PAD_ - 200), s = 200 + idx % (VT_PAD_ - 200);
            Vt[(size_t)bh * 64 * VT_PAD_ + (size_t)d * VT_PAD_ + s] = (_Float16)0.0f;
        }
    } else {
        int idx = (bid - 1024 - 1352 - 200 - cb8) * 256 + tid;  // 200*16 = 3200
        if (idx < 3200) {
            int t = idx >> 4, c = idx & 15;
            float ang = (float)t * powf(10000.0f, -(float)c / 16.0f);
            rtab[idx] = (float2){cosf(ang), sinf(ang)};
        }
    }
}

// ---------------------------------------------------------------- fused QKV GEMM (MFMA fp16, depth-2 counted-vmcnt pipeline, T2 swizzle)
// launch_bounds(256,3): allocator trims to ~68 VGPR + 64 acc -> 3 waves/SIMD
// (r14: occ 20->30%). RoPE cos/sin from precomputed rtab (no sincosf).
__global__ __launch_bounds__(256, 3) void gemm_qkv_k(
    const _Float16* __restrict__ xh,
    const _Float16* __restrict__ Wh,    // [3][512][512]
    const float* __restrict__ bq, const float* __restrict__ bk, const float* __restrict__ bv,
    const float2* __restrict__ rtab,    // [200][16] {cos,sin}
    _Float16* __restrict__ Qb, _Float16* __restrict__ Kb,
    _Float16* __restrict__ Vt,
    int nmt)
{
    int n = blockIdx.x;
    int mt, v;
    if ((nmt & 7) == 0) { int q8 = n & 7, i = n >> 3; mt = (i / 12) * 8 + q8; v = i % 12; }
    else               { mt = n / 12; v = n % 12; }
    int which = v >> 2;            // 0=Q 1=K 2=V
    int nt    = v & 3;             // n-tile (128 cols = 2 heads)
    int m0    = mt * 128;
    const _Float16* Wm = Wh + ((size_t)(which * 4 + nt) * 128) * 512;
    const float* bias = (which == 0) ? bq : (which == 1) ? bk : bv;

    __shared__ _Float16 As[3][128 * 32];
    __shared__ _Float16 Bs[3][128 * 32];

    int tid  = threadIdx.x;
    int w    = tid >> 6, lane = tid & 63;
    int quad = lane >> 4, l15 = lane & 15;
    int wm   = w >> 1,    wn  = w & 1;
    int srow = lane >> 2, scg = lane & 3;        // staging: row-in-seg, 16B colgroup (LDS slot)
    int scg_src = scg ^ ((srow >> 1) & 3);       // pre-swizzled global colgroup
    int rq = (l15 >> 1) & 3;                     // read-side swizzle term

    auto stage = [&](int buf, int k0) {
#pragma unroll
        for (int rr = 0; rr < 2; ++rr) {
            int seg = rr * 4 + w;               // 8 segments of 16 rows
            int row = seg * 16 + srow;
            gload16(xh + (size_t)(m0 + row) * 512 + k0 + scg_src * 8, As[buf] + seg * 512);
            gload16(Wm + (size_t)row * 512 + k0 + scg_src * 8, Bs[buf] + seg * 512);
        }
    };

    f32x4 acc[4][4];
#pragma unroll
    for (int m = 0; m < 4; ++m)
#pragma unroll
        for (int nn = 0; nn < 4; ++nn) acc[m][nn] = (f32x4){0.f, 0.f, 0.f, 0.f};

    stage(0, 0);
    stage(1, 32);
#pragma unroll
    for (int s = 0; s < 16; ++s) {
        if (s < 15) asm volatile("s_waitcnt vmcnt(4)" ::: "memory");
        else        asm volatile("s_waitcnt vmcnt(0)" ::: "memory");
        __builtin_amdgcn_s_barrier();
        __builtin_amdgcn_sched_barrier(0);
        const _Float16* Ab = As[s % 3];
        const _Float16* Bb = Bs[s % 3];
        f16x8 af[4], bf[4];
#pragma unroll
        for (int m = 0; m < 4; ++m)
            af[m] = *(const f16x8*)(Ab + (wm * 4 + m) * 512 + l15 * 32 + (quad ^ rq) * 8);
#pragma unroll
        for (int nn = 0; nn < 4; ++nn)
            bf[nn] = *(const f16x8*)(Bb + (wn * 4 + nn) * 512 + l15 * 32 + (quad ^ rq) * 8);
        if (s <= 13) stage((s + 2) % 3, (s + 2) * 32);
#pragma unroll
        for (int m = 0; m < 4; ++m)
#pragma unroll
            for (int nn = 0; nn < 4; ++nn)
                acc[m][nn] = __builtin_amdgcn_mfma_f32_16x16x32_f16(af[m], bf[nn], acc[m][nn], 0, 0, 0);
    }

    int h = nt * 2 + wn;   // head within matrix
    if (which < 2) {
        _Float16* dst = (which == 0) ? Qb : Kb;
        float sc = (which == 0) ? 0.125f : 1.0f;
#pragma unroll
        for (int m = 0; m < 4; ++m) {
#pragma unroll
            for (int r = 0; r < 4; ++r) {
                int row = m0 + wm * 64 + m * 16 + quad * 4 + r;
                int bl = row / T_, t = row % T_;
                float2 cssn = rtab[t * 16 + l15];
                float cs = cssn.x, sn = cssn.y;
                size_t base = ((size_t)(bl * 8 + h) * QK_ROWS_ + t) * 64;
                float av = acc[m][0][r] + bias[h * 64 + l15];
                float bv2 = acc[m][1][r] + bias[h * 64 + 16 + l15];
                dst[base + l15]      = (_Float16)((av * cs - bv2 * sn) * sc);
                dst[base + 16 + l15] = (_Float16)((bv2 * cs + av * sn) * sc);
                dst[base + 32 + l15] = (_Float16)((acc[m][2][r] + bias[h * 64 + 32 + l15]) * sc);
                dst[base + 48 + l15] = (_Float16)((acc[m][3][r] + bias[h * 64 + 48 + l15]) * sc);
            }
        }
    } else {
        // V: transpose-store to Vt[b][h][d][s]
#pragma unroll
        for (int nn = 0; nn < 4; ++nn) {
            int ch = nn * 16 + l15;
            float bval = bias[h * 64 + ch];
#pragma unroll
            for (int m = 0; m < 4; ++m) {
                int r0 = m0 + wm * 64 + m * 16 + quad * 4;   // 4 consecutive rows, %4==0
                int t0v = r0 % T_;
                if (t0v <= 196) {
                    int bl = r0 / T_;
                    f16x4 v4 = {(_Float16)(acc[m][nn][0] + bval),
                                (_Float16)(acc[m][nn][1] + bval),
                                (_Float16)(acc[m][nn][2] + bval),
                                (_Float16)(acc[m][nn][3] + bval)};
                    *(f16x4*)(Vt + ((size_t)(bl * 8 + h) * 64 + ch) * VT_PAD_ + t0v) = v4;
                } else {
#pragma unroll
                    for (int r = 0; r < 4; ++r) {
                        int rw = r0 + r;
                        int bl = rw / T_, s = rw % T_;
                        Vt[((size_t)(bl * 8 + h) * 64 + ch) * VT_PAD_ + s] = (_Float16)(acc[m][nn][r] + bval);
                    }
                }
            }
        }
    }
}

// ---------------------------------------------------------------- fused MFMA attention (512 thr, 8 waves, 1 head/wave; fp16)
// flat grid 13*CB, XCD-swizzled (b locality) + LPT heavy-first.
// launch_bounds(512,4): (512,6) spills (r15: VGPR 60->40, WRITE 51->169MB).
__global__ __launch_bounds__(512, 4) void attn_fused_k(
    const _Float16* __restrict__ Qb, const _Float16* __restrict__ Kb,
    const _Float16* __restrict__ Vt,
    const float* __restrict__ wtab,   // [8][208][208]
    const float* __restrict__ wmix,
    _Float16* __restrict__ ao)
{
    int n    = blockIdx.x;
    int xcd  = n & 7, slot = n >> 3;
    int i_tile = 12 - (slot % 13);       // LPT: heaviest (nst=13) dispatched first
    int b      = (slot / 13) * 8 + xcd;

    int tid  = threadIdx.x;
    int wave = tid >> 6, lane = tid & 63;
    int quad = lane >> 4, l15 = lane & 15;
    int t0   = i_tile * 16;
    int nst  = i_tile + 1;         // s-tiles needed (s <= t0+15)
    int smax = nst * 16;
    int lim  = smax < 200 ? smax : 200;  // valid P columns

    __shared__ _Float16 Pt[8][16][P_PAD_];         // 51,200 B
    __shared__ float mixs[64];                     //    256 B
    __shared__ f16x2 invt[8][16];                  //    512 B

    if (tid < 64) mixs[tid] = wmix[tid];

    // ---- phase 1: QK^T -> exp -> *w -> Pt (unnormalized); wave = head g
    {
        int g = wave;
        int trow = quad * 4;
        const _Float16* Qg = Qb + (size_t)(b * 8 + g) * QK_ROWS_ * 64;
        const _Float16* Kg = Kb + (size_t)(b * 8 + g) * QK_ROWS_ * 64;
        f16x8 a0 = *(const f16x8*)(Qg + (size_t)(t0 + l15) * 64 + quad * 8);
        f16x8 a1 = *(const f16x8*)(Qg + (size_t)(t0 + l15) * 64 + quad * 8 + 32);
        const float* wg = wtab + ((size_t)g * 208 + t0) * 208;

        // rolling depth-2 ring (compile-time st%3 indices)
        f16x8 kr0[3], kr1[3];
        float wr[3][4];
        kr0[0] = *(const f16x8*)(Kg + (size_t)l15 * 64 + quad * 8);
        kr1[0] = *(const f16x8*)(Kg + (size_t)l15 * 64 + quad * 8 + 32);
#pragma unroll
        for (int r = 0; r < 4; ++r) wr[0][r] = wg[(trow + r) * 208 + l15];
        if (nst > 1) {
            kr0[1] = *(const f16x8*)(Kg + (size_t)(16 + l15) * 64 + quad * 8);
            kr1[1] = *(const f16x8*)(Kg + (size_t)(16 + l15) * 64 + quad * 8 + 32);
#pragma unroll
            for (int r = 0; r < 4; ++r) wr[1][r] = wg[(trow + r) * 208 + 16 + l15];
        }
        __builtin_amdgcn_sched_barrier(0);   // pin prologue load issue

        float sum[4] = {0.f, 0.f, 0.f, 0.f};
        __builtin_amdgcn_s_setprio(1);
#pragma unroll
        for (int st = 0; st < 13; ++st) if (st < nst) {
            if (st + 2 < nst) {              // prefetch st+2 before consuming st
                int sl = (st + 2) % 3;
                kr0[sl] = *(const f16x8*)(Kg + (size_t)((st + 2) * 16 + l15) * 64 + quad * 8);
                kr1[sl] = *(const f16x8*)(Kg + (size_t)((st + 2) * 16 + l15) * 64 + quad * 8 + 32);
#pragma unroll
                for (int r = 0; r < 4; ++r) wr[sl][r] = wg[(trow + r) * 208 + (st + 2) * 16 + l15];
                __builtin_amdgcn_sched_barrier(0);   // don't sink the prefetch
            }
            int cl = st % 3;
            f32x4 c = {0.f, 0.f, 0.f, 0.f};
            c = __builtin_amdgcn_mfma_f32_16x16x32_f16(a0, kr0[cl], c, 0, 0, 0);
            c = __builtin_amdgcn_mfma_f32_16x16x32_f16(a1, kr1[cl], c, 0, 0, 0);
            int s = st * 16 + l15;
            bool diag = (st == nst - 1);
#pragma unroll
            for (int r = 0; r < 4; ++r) {
                int t = t0 + trow + r;
                float e = (!diag || s <= t) ? __expf(c[r]) : 0.f;
                sum[r] += e;
                if (s < 200) Pt[g][trow + r][s] = (_Float16)(e * wr[cl][r]);
            }
        }
        __builtin_amdgcn_s_setprio(0);
#pragma unroll
        for (int r = 0; r < 4; ++r) {
            float sm = sum[r];
            sm += __shfl_xor(sm, 1);
            sm += __shfl_xor(sm, 2);
            sm += __shfl_xor(sm, 4);
            sm += __shfl_xor(sm, 8);
            if (l15 == 0) {
                _Float16 ih = (_Float16)(1.0f / sm);
                invt[g][trow + r] = (f16x2){ih, ih};
            }
        }
    }
    __syncthreads();

    // ---- phase 2: normalize (×invt) + in-place 8x8 head mix, packed f16x2
    {
        f16x2 mx[64];
#pragma unroll
        for (int i = 0; i < 64; ++i) {
            _Float16 mh = (_Float16)mixs[i];
            mx[i] = (f16x2){mh, mh};
        }
        int nitems = lim << 3;             // 16 tloc x (lim/2) pairs
        for (int idx = tid; idx < nitems; idx += 512) {
            int tloc = idx & 15;
            int sp   = (idx >> 4) << 1;    // even s, < lim <= 200
            f16x2 pv[8];
#pragma unroll
            for (int g = 0; g < 8; ++g) pv[g] = *(const f16x2*)&Pt[g][tloc][sp];
#pragma unroll
            for (int g = 0; g < 8; ++g) pv[g] = pv[g] * invt[g][tloc];
#pragma unroll
            for (int ho = 0; ho < 8; ++ho) {
                f16x2 o = mx[ho * 8] * pv[0];
#pragma unroll
                for (int g = 1; g < 8; ++g) o += mx[ho * 8 + g] * pv[g];
                *(f16x2*)&Pt[ho][tloc][sp] = o;
            }
        }
    }
    __syncthreads();

    // ---- phase 3: PV via MFMA (fp16); wave = head. A-frag slots cc >= lim
    // are masked/nonexistent -> zero (b*0=0; Vt zero-padded past 200).
    // V prefetched depth-2 with pinned issue.
    {
        int nk = (nst + 1) >> 1;       // k-steps of 32 over s
        int hda = wave;
        const _Float16* Vh = Vt + (size_t)(b * 8 + hda) * 64 * VT_PAD_;
        f32x4 c4[4];
#pragma unroll
        for (int n2 = 0; n2 < 4; ++n2) c4[n2] = (f32x4){0.f, 0.f, 0.f, 0.f};
        f16x8 vb[2][4];
#pragma unroll
        for (int n2 = 0; n2 < 4; ++n2)
            vb[0][n2] = *(const f16x8*)(Vh + (size_t)(n2 * 16 + l15) * VT_PAD_ + quad * 8);
        __builtin_amdgcn_s_setprio(1);
#pragma unroll
        for (int ks = 0; ks < 7; ++ks) if (ks < nk) {
            if (ks + 1 < nk) {
#pragma unroll
                for (int n2 = 0; n2 < 4; ++n2)
                    vb[(ks + 1) & 1][n2] = *(const f16x8*)(Vh + (size_t)(n2 * 16 + l15) * VT_PAD_ + (ks + 1) * 32 + quad * 8);
                __builtin_amdgcn_sched_barrier(0);   // don't sink the prefetch
            }
            int cc = ks * 32 + quad * 8;
            bool oob = cc >= lim;
            int cl = oob ? 0 : cc;
            f16x8 a = *(const f16x8*)(&Pt[hda][l15][cl]);
            if (oob) {
#pragma unroll
                for (int j = 0; j < 8; ++j) a[j] = (_Float16)0.0f;
            }
#pragma unroll
            for (int n2 = 0; n2 < 4; ++n2)
                c4[n2] = __builtin_amdgcn_mfma_f32_16x16x32_f16(a, vb[ks & 1][n2], c4[n2], 0, 0, 0);
        }
        __builtin_amdgcn_s_setprio(0);
#pragma unroll
        for (int n2 = 0; n2 < 4; ++n2)
#pragma unroll
            for (int r = 0; r < 4; ++r) {
                int t = t0 + quad * 4 + r;
                if (t < 200)
                    ao[((size_t)(b * T_ + t)) * 512 + hda * 64 + n2 * 16 + l15] = (_Float16)c4[n2][r];
            }
    }
}

// ---------------------------------------------------------------- out projection (MFMA fp16, pipeline, T2 swizzle) * gamma,
// FUSED with pos/neg logits: po = val*pe written directly; neg partials
// (64-col slices) reduced over l15 and atomicAdd'ed. No lf buffer.
__global__ __launch_bounds__(256, 3) void gemm_out_k(
    const _Float16* __restrict__ Ah, const _Float16* __restrict__ Woh,
    const float* __restrict__ bo, const float* __restrict__ gamma,
    const float* __restrict__ emb, const int* __restrict__ pos,
    const int* __restrict__ neg, float* __restrict__ out,
    int bt0, int nmt)
{
    int n = blockIdx.x;
    int mt, nt;
    if ((nmt & 7) == 0) { int q8 = n & 7, i = n >> 3; mt = (i / 4) * 8 + q8; nt = i % 4; }
    else               { mt = n / 4; nt = n % 4; }
    int m0 = mt * 128;
    const _Float16* Wm = Woh + (size_t)nt * 128 * 512;

    __shared__ _Float16 As[3][128 * 32];
    __shared__ _Float16 Bs[3][128 * 32];

    int tid  = threadIdx.x;
    int w    = tid >> 6, lane = tid & 63;
    int quad = lane >> 4, l15 = lane & 15;
    int wm   = w >> 1,    wn  = w & 1;
    int srow = lane >> 2, scg = lane & 3;
    int scg_src = scg ^ ((srow >> 1) & 3);
    int rq = (l15 >> 1) & 3;

    auto stage = [&](int buf, int k0) {
#pragma unroll
        for (int rr = 0; rr < 2; ++rr) {
            int seg = rr * 4 + w;
            int row = seg * 16 + srow;
            gload16(Ah + (size_t)(m0 + row) * 512 + k0 + scg_src * 8, As[buf] + seg * 512);
            gload16(Wm + (size_t)row * 512 + k0 + scg_src * 8, Bs[buf] + seg * 512);
        }
    };

    f32x4 acc[4][4];
#pragma unroll
    for (int m = 0; m < 4; ++m)
#pragma unroll
        for (int nn = 0; nn < 4; ++nn) acc[m][nn] = (f32x4){0.f, 0.f, 0.f, 0.f};

    stage(0, 0);
    stage(1, 32);
#pragma unroll
    for (int s = 0; s < 16; ++s) {
        if (s < 15) asm volatile("s_waitcnt vmcnt(4)" ::: "memory");
        else        asm volatile("s_waitcnt vmcnt(0)" ::: "memory");
        __builtin_amdgcn_s_barrier();
        __builtin_amdgcn_sched_barrier(0);
        const _Float16* Ab = As[s % 3];
        const _Float16* Bb = Bs[s % 3];
        f16x8 af[4], bf[4];
#pragma unroll
        for (int m = 0; m < 4; ++m)
            af[m] = *(const f16x8*)(Ab + (wm * 4 + m) * 512 + l15 * 32 + (quad ^ rq) * 8);
#pragma unroll
        for (int nn = 0; nn < 4; ++nn)
            bf[nn] = *(const f16x8*)(Bb + (wn * 4 + nn) * 512 + l15 * 32 + (quad ^ rq) * 8);
        if (s <= 13) stage((s + 2) % 3, (s + 2) * 32);
#pragma unroll
        for (int m = 0; m < 4; ++m)
#pragma unroll
            for (int nn = 0; nn < 4; ++nn)
                acc[m][nn] = __builtin_amdgcn_mfma_f32_16x16x32_f16(af[m], bf[nn], acc[m][nn], 0, 0, 0);
    }

    // fused epilogue: lf = (acc+bo)*gamma; po = lf*pe; neg += lf.ne (atomic)
#pragma unroll
    for (int m = 0; m < 4; ++m) {
#pragma unroll
        for (int r = 0; r < 4; ++r) {
            int row = m0 + wm * 64 + m * 16 + quad * 4 + r;
            float gg = gamma[row % T_];
            int pr = pos[row], nr = neg[row];
            const float* pe = emb + (size_t)pr * 512;
            const float* ne = emb + (size_t)nr * 512;
            float* po = out + (size_t)(bt0 + row) * 512;
            float s = 0.f;
#pragma unroll
            for (int nn = 0; nn < 4; ++nn) {
                int col = nt * 128 + wn * 64 + nn * 16 + l15;
                float val = (acc[m][nn][r] + bo[col]) * gg;
                po[col] = val * pe[col];
                s += val * ne[col];
            }
            s += __shfl_xor(s, 1);
            s += __shfl_xor(s, 2);
            s += __shfl_xor(s, 4);
            s += __shfl_xor(s, 8);
            if (l15 == 0)
                atomicAdd(out + (size_t)POS_OUT_ + bt0 + row, s);
        }
    }
}

// ----------------------------------------------------------------
extern "C" void kernel_launch(void* const* d_in, const int* in_sizes, int n_in,
                              void* d_out, int out_size, void* d_ws, size_t ws_size,
                              hipStream_t stream)
{
    const int* logs = (const int*)d_in[1];
    const int* pos  = (const int*)d_in[2];
    const int* neg  = (const int*)d_in[3];
    const float* emb = (const float*)d_in[4];
    const float* tw  = (const float*)d_in[5];
    const float* ta  = (const float*)d_in[6];
    const float* tb  = (const float*)d_in[7];
    const float* tg  = (const float*)d_in[8];
    const float* Wq  = (const float*)d_in[9];
    const float* bq  = (const float*)d_in[10];
    const float* Wk  = (const float*)d_in[11];
    const float* bk  = (const float*)d_in[12];
    const float* Wv  = (const float*)d_in[13];
    const float* bv  = (const float*)d_in[14];
    const float* wmix= (const float*)d_in[15];
    const float* Wo  = (const float*)d_in[16];
    const float* bo  = (const float*)d_in[17];

    // Per-b buffer bytes: xh + Qb + Kb + Vt + ao(fp16)
    const size_t PER_B = (size_t)T_ * C_ * 2            // xh      204,800
                       + (size_t)8 * QK_ROWS_ * 64 * 2  // Qb      212,992
                       + (size_t)8 * QK_ROWS_ * 64 * 2  // Kb      212,992
                       + (size_t)8 * 64 * VT_PAD_ * 2   // Vt      229,376
                       + (size_t)T_ * C_ * 2;           // ao      204,800
    const size_t SZ_WH = (size_t)4 * 512 * 512 * 2;     // 2,097,152
    const size_t SZ_WT = (size_t)8 * 208 * 208 * 4;     // 1,384,448
    const size_t SZ_RT = (size_t)200 * 16 * 8;          //    25,600

    int CB = (ws_size >= SZ_WH + SZ_WT + SZ_RT + PER_B * B_) ? B_ : 32;
    int nch = B_ / CB;
    int CM = CB * T_;
    int NMT = CM / 128;            // m-tiles

    char* p = (char*)d_ws;
    _Float16*       Wh   = (_Float16*)p;  p += SZ_WH;
    float*          wtab = (float*)p;     p += SZ_WT;
    float2*         rtab = (float2*)p;    p += SZ_RT;
    _Float16*       xh   = (_Float16*)p;  p += (size_t)CM * C_ * 2;
    _Float16*       Qb   = (_Float16*)p;  p += (size_t)CB * 8 * QK_ROWS_ * 64 * 2;
    _Float16*       Kb   = (_Float16*)p;  p += (size_t)CB * 8 * QK_ROWS_ * 64 * 2;
    _Float16*       Vt   = (_Float16*)p;  p += (size_t)CB * 8 * 64 * VT_PAD_ * 2;
    _Float16*       aoh  = (_Float16*)p;

    int cb8 = CB * 8;
    int npro = 1024 + 1352 + 200 + cb8 + 13;
    prologue_k<<<npro, 256, 0, stream>>>(Wq, Wk, Wv, Wo, Wh, tw, ta, tb, wtab,
                                         (float*)d_out, Qb, Kb, Vt, rtab, cb8);

    for (int c = 0; c < nch; ++c) {
        int bt0 = c * CM;
        gather_shift_k<<<2048, 256, 0, stream>>>(emb, logs + bt0, xh);
        gemm_qkv_k<<<NMT * 12, 256, 0, stream>>>(xh, Wh, bq, bk, bv, rtab, Qb, Kb, Vt, NMT);
        attn_fused_k<<<13 * CB, 512, 0, stream>>>(Qb, Kb, Vt, wtab, wmix, aoh);
        gemm_out_k<<<NMT * 4, 256, 0, stream>>>(aoh, Wh + (size_t)3 * 512 * 512, bo, tg,
                                                emb, pos + bt0, neg + bt0, (float*)d_out, bt0, NMT);
    }
}